// Round 8
// baseline (610.203 us; speedup 1.0000x reference)
//
#include <hip/hip_runtime.h>

#define NG 8000
#define NHALF 4000
#define TS 1440
#define NOUT 32
#define LENFT 72
#define DTC (1.0f/24.0f)
#define NEARZEROC 1e-5f

// gfx950 hardware transcendentals (base-2). Pure ops -> non-volatile asm (CSE ok).
__device__ __forceinline__ float fexp2(float x) {
  float r; asm("v_exp_f32 %0, %1" : "=v"(r) : "v"(x)); return r;
}
__device__ __forceinline__ float flog2(float x) {
  float r; asm("v_log_f32 %0, %1" : "=v"(r) : "v"(x)); return r;
}

// ---------------------------------------------------------------------------
// Kernel 1: per-cell constants + normalized routing weights
// ---------------------------------------------------------------------------
__global__ __launch_bounds__(256) void precompute_kernel(
    const float* __restrict__ p1, const float* __restrict__ p2,
    const float* __restrict__ ac_all,
    float* __restrict__ Cst,   // 16 * NG floats (SoA)
    float* __restrict__ W)     // LENFT * NG floats (k-major)
{
  int n = blockIdx.x * 256 + threadIdx.x;
  if (n >= NG) return;
  const float* r = p1 + n * 19;
  float BETA   = 1.0f   + r[0]  * 5.0f;
  float FC     = 50.0f  + r[1]  * 950.0f;
  float K0     = 0.05f  + r[2]  * 0.85f;
  float K1     = 0.01f  + r[3]  * 0.49f;
  float K2     = 0.001f + r[4]  * 0.199f;
  float LP     = 0.2f   + r[5]  * 0.8f;
  float PERC   =          r[6]  * 10.0f;
  float UZL    =          r[7]  * 100.0f;
  float TT     = -2.5f  + r[8]  * 5.0f;
  float CFMAX  = 0.5f   + r[9]  * 9.5f;
  float CFR    =          r[10] * 0.1f;
  float CWH    =          r[11] * 0.2f;
  float BETAET = 0.3f   + r[12] * 4.7f;
  float Cpar   =          r[13];
  float RT     =          r[14] * 20.0f;
  float AC     =          r[15] * 2500.0f;
  float F0     = 120.0f + r[16] * 2760.0f;
  float FMIN   =          r[17];
  float ALPHA  = 0.5f   + r[18] * 4.5f;

  float ac  = ac_all[n];
  float fmx = DTC * F0 * (FMIN + (1.0f - FMIN) * expf(-powf(ac / (AC + 1.0f), 1.0f / ALPHA)));

  Cst[ 0*NG+n] = TT;            Cst[ 1*NG+n] = CFMAX * DTC;
  Cst[ 2*NG+n] = CFR*CFMAX*DTC; Cst[ 3*NG+n] = CWH;
  Cst[ 4*NG+n] = fmx;           Cst[ 5*NG+n] = 1.0f / FC;
  Cst[ 6*NG+n] = BETA;          Cst[ 7*NG+n] = FC;
  Cst[ 8*NG+n] = Cpar;          Cst[ 9*NG+n] = 1.0f / (LP * FC);
  Cst[10*NG+n] = BETAET;        Cst[11*NG+n] = PERC * DTC;
  Cst[12*NG+n] = K0 * DTC;      Cst[13*NG+n] = UZL;
  Cst[14*NG+n] = K1 * DTC;      Cst[15*NG+n] = K2 * DTC;

  // routing weights (gamma kernel), normalized
  float a   = fmaxf(p2[n*3+0] * 5.0f,  0.01f);
  float b   = fmaxf(p2[n*3+1] * 12.0f, 0.01f);
  float lag = p2[n*3+2] * 48.0f + RT;
  float am1 = a - 1.0f, invb = 1.0f / b;
  float sum = 0.0f;
  for (int k = 0; k < LENFT; k++) {
    float s  = (k + 0.5f) - lag;
    float sm = fmaxf(s, 1e-6f);
    float wv = (s > 0.0f) ? expf(am1 * logf(sm) - sm * invb) : 0.0f;
    sum += wv;
  }
  float inv = 1.0f / (sum + 1e-8f);
  for (int k = 0; k < LENFT; k++) {
    float s  = (k + 0.5f) - lag;
    float sm = fmaxf(s, 1e-6f);
    float wv = (s > 0.0f) ? expf(am1 * logf(sm) - sm * invb) : 0.0f;
    W[k*NG + n] = wv * inv;
  }
}

// ---------------------------------------------------------------------------
// Kernel 2: sequential HBV scan, ILP-2.
// Round-6/7 lessons: 1 wave/SIMD (64-thr blocks) = chain-bound 400 cyc/step;
// 512-thr blocks = 16 CUs = per-CU BW-bound (worse). Parallelism is capped at
// 125 waves, so instead interleave TWO independent cells per thread: the two
// dependency chains fill each other's stalls. 4000 threads = 63 blocks x 64,
// 63 CUs: BW needs ~0.7 TB/s < 63-CU ceiling ~1.4 TB/s.
// ---------------------------------------------------------------------------
struct HbvConst {
  float TT, CFMAXDT, CFRDT, CWH, FMX, IFC, BETA, FC, C, ILF, BETAET,
        PERCDT, K0DT, UZL, K1DT, K2DT;
};

__device__ __forceinline__ void load_const(const float* __restrict__ Cst,
                                           int n, HbvConst& c) {
  c.TT    =Cst[ 0*NG+n]; c.CFMAXDT=Cst[ 1*NG+n]; c.CFRDT =Cst[ 2*NG+n];
  c.CWH   =Cst[ 3*NG+n]; c.FMX    =Cst[ 4*NG+n]; c.IFC   =Cst[ 5*NG+n];
  c.BETA  =Cst[ 6*NG+n]; c.FC     =Cst[ 7*NG+n]; c.C     =Cst[ 8*NG+n];
  c.ILF   =Cst[ 9*NG+n]; c.BETAET =Cst[10*NG+n]; c.PERCDT=Cst[11*NG+n];
  c.K0DT  =Cst[12*NG+n]; c.UZL    =Cst[13*NG+n]; c.K1DT  =Cst[14*NG+n];
  c.K2DT  =Cst[15*NG+n];
}

__device__ __forceinline__ float hbv_step(float P, float Tm, float PET,
    const HbvConst& c, float& SP, float& MW, float& SM, float& SUZ, float& SLZ)
{
  float rain = (Tm >= c.TT) ? P : 0.0f;
  float snow = P - rain;
  SP += snow;
  float dT   = Tm - c.TT;
  float melt = fminf(fmaxf(c.CFMAXDT * dT, 0.0f), SP);
  MW += melt; SP -= melt;
  float refr = fminf(fmaxf(c.CFRDT * (-dT), 0.0f), MW);
  SP += refr; MW -= refr;
  float tosoil = fmaxf(MW - c.CWH * SP, 0.0f);
  MW -= tosoil;
  float win   = rain + tosoil;
  float infil = fminf(win, c.FMX);
  float qie   = win - infil;
  float sw    = fminf(fexp2(c.BETA * flog2(SM * c.IFC)), 1.0f);
  float rech  = infil * sw;
  SM += infil - rech;
  float excess = fmaxf(SM - c.FC, 0.0f);
  SM -= excess;
  float cap = fminf(SLZ, c.C * SLZ * (1.0f - fminf(SM * c.IFC, 1.0f)));
  SM += cap; SLZ -= cap;
  float ef = fminf(fexp2(c.BETAET * flog2(SM * c.ILF)), 1.0f);
  float et = fminf(PET * ef, SM);
  SM = fmaxf(SM - et, NEARZEROC);
  SUZ += rech + excess;
  float perc = fminf(SUZ, c.PERCDT);
  SUZ -= perc;
  float q0 = c.K0DT * fmaxf(SUZ - c.UZL, 0.0f);
  SUZ -= q0;
  float q1 = c.K1DT * SUZ;
  SUZ -= q1;
  SLZ += perc;
  float q2 = c.K2DT * SLZ;
  SLZ -= q2;
  return qie + q0 + q1 + q2;
}

// load 4 steps of (P,T,PET) for both cells as float3 vectors
#define LOAD4_2(A0, A1, T0)                                                   \
  { _Pragma("unroll")                                                         \
    for (int i_ = 0; i_ < 4; i_++) {                                          \
      A0[i_] = *reinterpret_cast<const float3*>(xp0 + ((T0) + i_) * (NG * 3));\
      A1[i_] = *reinterpret_cast<const float3*>(xp1 + ((T0) + i_) * (NG * 3));\
    } }

__global__ __launch_bounds__(64, 1) void scan_kernel(
    const float* __restrict__ x, const float* __restrict__ Cst,
    float* __restrict__ Q)
{
  int n0 = blockIdx.x * 64 + threadIdx.x;
  if (n0 >= NHALF) return;
  int n1 = n0 + NHALF;

  HbvConst c0, c1;
  load_const(Cst, n0, c0);
  load_const(Cst, n1, c1);

  float SP0=1e-3f, MW0=1e-3f, SM0=1e-3f, SUZ0=1e-3f, SLZ0=1e-3f;
  float SP1=1e-3f, MW1=1e-3f, SM1=1e-3f, SUZ1=1e-3f, SLZ1=1e-3f;

  const float* xp0 = x + n0 * 3;
  const float* xp1 = x + n1 * 3;
  float* Qp = Q + n0;

  float3 a0[4], a1[4], b0[4], b1[4];
  LOAD4_2(a0, a1, 0);
  for (int tb = 0; tb < TS; tb += 8) {
    LOAD4_2(b0, b1, tb + 4);                   // prefetch next 4 steps
    #pragma unroll
    for (int i = 0; i < 4; i++) {
      float q0 = hbv_step(a0[i].x, a0[i].y, a0[i].z, c0, SP0, MW0, SM0, SUZ0, SLZ0);
      float q1 = hbv_step(a1[i].x, a1[i].y, a1[i].z, c1, SP1, MW1, SM1, SUZ1, SLZ1);
      Qp[(tb + i) * NG]          = q0;
      Qp[(tb + i) * NG + NHALF]  = q1;
    }
    if (tb + 8 < TS) LOAD4_2(a0, a1, tb + 8);
    #pragma unroll
    for (int i = 0; i < 4; i++) {
      float q0 = hbv_step(b0[i].x, b0[i].y, b0[i].z, c0, SP0, MW0, SM0, SUZ0, SLZ0);
      float q1 = hbv_step(b1[i].x, b1[i].y, b1[i].z, c1, SP1, MW1, SM1, SUZ1, SLZ1);
      Qp[(tb + 4 + i) * NG]         = q0;
      Qp[(tb + 4 + i) * NG + NHALF] = q1;
    }
  }
}

// ---------------------------------------------------------------------------
// Kernel 3: fused routing FIR (72 taps) + partial einsum.
// LDS-pipe was the bottleneck (~470 b32 ds-reads/thread/subtile). This round:
// einsum G lives in registers (global float4, L2-hot) and Rs is read as
// broadcast float4 (pad 68) -> einsum ds ops 320 -> 64 per thread/subtile.
// ---------------------------------------------------------------------------
#define TTILE 32
#define NTILES_T 45          // 1440 / 32
#define NSPLIT 25
#define SUBS 5               // subtiles per split (25*5*64 = 8000)
#define QROWS (TTILE + 71)   // 103

__global__ __launch_bounds__(256, 2) void route_kernel(
    const float* __restrict__ Q, const float* __restrict__ W,
    const float* __restrict__ topo, const float* __restrict__ areas,
    float* __restrict__ Par)   // [NSPLIT][TS][NOUT]
{
  __shared__ float Qs[QROWS][64];   // 26.4 KB
  __shared__ float Ws[LENFT][64];   // 18.4 KB
  __shared__ float Rs[TTILE][68];   //  8.7 KB (pad 68: float4-aligned rows)

  int tile  = blockIdx.x;           // 0..44
  int split = blockIdx.y;           // 0..24
  int t0    = tile * TTILE;
  int tid   = threadIdx.x;

  int nn = tid & 63;                // conv: cell within subtile
  int tc = (tid >> 6) * 8;          // conv: 8 consecutive t-rows
  int oe = tid & 31;                // einsum: outlet
  int te = (tid >> 5) * 4;          // einsum: 4 consecutive t-rows

  float acc_out[4] = {0.f, 0.f, 0.f, 0.f};

  for (int sub = 0; sub < SUBS; sub++) {
    int n0 = (split * SUBS + sub) * 64;

    // G for this subtile into registers (coalesced row reads, L2-hot);
    // issued early so latency hides under staging + conv.
    float4 Greg[16];
    #pragma unroll
    for (int g4 = 0; g4 < 16; g4++) {
      float4 tv = *reinterpret_cast<const float4*>(&topo[oe * NG + n0 + g4 * 4]);
      float4 av = *reinterpret_cast<const float4*>(&areas[n0 + g4 * 4]);
      Greg[g4] = make_float4(tv.x * av.x, tv.y * av.y, tv.z * av.z, tv.w * av.w);
    }

    if (sub) __syncthreads();       // prev einsum reads done before reload
    // ---- load Q tile (rows t0-71 .. t0+31) and W tile ----
    for (int idx = tid; idx < QROWS * 64; idx += 256) {
      int rr = idx >> 6, cc = idx & 63;
      int t  = t0 - 71 + rr;
      Qs[rr][cc] = (t >= 0) ? Q[t * NG + n0 + cc] : 0.0f;
    }
    for (int idx = tid; idx < LENFT * 64; idx += 256) {
      int k = idx >> 6, cc = idx & 63;
      Ws[k][cc] = W[k * NG + n0 + cc];
    }
    __syncthreads();

    // ---- conv: 8 outputs/thread, sliding 8-register window over Q rows ----
    float acc[8];
    float qwin[8];
    #pragma unroll
    for (int i = 0; i < 8; i++) { acc[i] = 0.0f; qwin[i] = Qs[tc + i][nn]; }
    #pragma unroll
    for (int kk = 0; kk < LENFT; kk++) {
      float w = Ws[71 - kk][nn];
      #pragma unroll
      for (int i = 0; i < 8; i++) acc[i] += w * qwin[i];
      #pragma unroll
      for (int i = 0; i < 7; i++) qwin[i] = qwin[i + 1];
      if (kk < 71) qwin[7] = Qs[tc + 8 + kk][nn];
    }
    #pragma unroll
    for (int i = 0; i < 8; i++) Rs[tc + i][nn] = acc[i];
    __syncthreads();

    // ---- einsum: 4 (t,o) outputs/thread; Rs as broadcast float4 ----
    #pragma unroll
    for (int g4 = 0; g4 < 16; g4++) {
      float4 g = Greg[g4];
      #pragma unroll
      for (int p = 0; p < 4; p++) {
        float4 r = *reinterpret_cast<const float4*>(&Rs[te + p][g4 * 4]);
        acc_out[p] += r.x * g.x + r.y * g.y + r.z * g.z + r.w * g.w;
      }
    }
  }

  #pragma unroll
  for (int p = 0; p < 4; p++) {
    int tg = t0 + te + p;           // always < 1440 (45*32 exact)
    Par[(split * TS + tg) * NOUT + oe] = acc_out[p];
  }
}

// ---------------------------------------------------------------------------
// Kernel 4: reduce partials over the 25 n-splits
// ---------------------------------------------------------------------------
__global__ __launch_bounds__(256) void reduce_kernel(
    const float* __restrict__ Par, float* __restrict__ out)
{
  int i = blockIdx.x * 256 + threadIdx.x;
  if (i < TS * NOUT) {
    float s = 0.0f;
    #pragma unroll
    for (int sp = 0; sp < NSPLIT; sp++) s += Par[sp * (TS * NOUT) + i];
    out[i] = s;
  }
}

// ---------------------------------------------------------------------------
extern "C" void kernel_launch(void* const* d_in, const int* in_sizes, int n_in,
                              void* d_out, int out_size, void* d_ws, size_t ws_size,
                              hipStream_t stream)
{
  const float* x_phy  = (const float*)d_in[0];
  const float* ac_all = (const float*)d_in[1];
  // d_in[2] = elev_all (unused by reference)
  const float* topo   = (const float*)d_in[3];
  const float* areas  = (const float*)d_in[4];
  const float* p1     = (const float*)d_in[5];
  const float* p2     = (const float*)d_in[6];
  float* out = (float*)d_out;

  char* ws = (char*)d_ws;
  float* Q   = (float*)(ws);                                  // 46,080,000 B
  float* W   = (float*)(ws + 46080000);                       //  2,304,000 B
  float* Cst = (float*)(ws + 46080000 + 2304000);             //    512,000 B
  float* Par = (float*)(ws + 46080000 + 2304000 + 512000);    //  4,608,000 B

  hipLaunchKernelGGL(precompute_kernel, dim3(32), dim3(256), 0, stream,
                     p1, p2, ac_all, Cst, W);
  hipLaunchKernelGGL(scan_kernel, dim3((NHALF + 63) / 64), dim3(64), 0, stream,
                     x_phy, Cst, Q);
  hipLaunchKernelGGL(route_kernel, dim3(NTILES_T, NSPLIT), dim3(256), 0, stream,
                     Q, W, topo, areas, Par);
  hipLaunchKernelGGL(reduce_kernel, dim3((TS * NOUT + 255) / 256), dim3(256), 0, stream,
                     Par, out);
}

// Round 9
// 433.658 us; speedup vs baseline: 1.4071x; 1.4071x over previous
//
#include <hip/hip_runtime.h>

#define NG 8000
#define TS 1440
#define NOUT 32
#define LENFT 72
#define DTC (1.0f/24.0f)
#define NEARZEROC 1e-5f

// gfx950 hardware transcendentals (base-2). Pure ops -> non-volatile asm (CSE ok).
__device__ __forceinline__ float fexp2(float x) {
  float r; asm("v_exp_f32 %0, %1" : "=v"(r) : "v"(x)); return r;
}
__device__ __forceinline__ float flog2(float x) {
  float r; asm("v_log_f32 %0, %1" : "=v"(r) : "v"(x)); return r;
}

// ---------------------------------------------------------------------------
// Kernel 1: per-cell constants + normalized routing weights
// ---------------------------------------------------------------------------
__global__ __launch_bounds__(256) void precompute_kernel(
    const float* __restrict__ p1, const float* __restrict__ p2,
    const float* __restrict__ ac_all,
    float* __restrict__ Cst,   // 16 * NG floats (SoA)
    float* __restrict__ W)     // LENFT * NG floats (k-major)
{
  int n = blockIdx.x * 256 + threadIdx.x;
  if (n >= NG) return;
  const float* r = p1 + n * 19;
  float BETA   = 1.0f   + r[0]  * 5.0f;
  float FC     = 50.0f  + r[1]  * 950.0f;
  float K0     = 0.05f  + r[2]  * 0.85f;
  float K1     = 0.01f  + r[3]  * 0.49f;
  float K2     = 0.001f + r[4]  * 0.199f;
  float LP     = 0.2f   + r[5]  * 0.8f;
  float PERC   =          r[6]  * 10.0f;
  float UZL    =          r[7]  * 100.0f;
  float TT     = -2.5f  + r[8]  * 5.0f;
  float CFMAX  = 0.5f   + r[9]  * 9.5f;
  float CFR    =          r[10] * 0.1f;
  float CWH    =          r[11] * 0.2f;
  float BETAET = 0.3f   + r[12] * 4.7f;
  float Cpar   =          r[13];
  float RT     =          r[14] * 20.0f;
  float AC     =          r[15] * 2500.0f;
  float F0     = 120.0f + r[16] * 2760.0f;
  float FMIN   =          r[17];
  float ALPHA  = 0.5f   + r[18] * 4.5f;

  float ac  = ac_all[n];
  float fmx = DTC * F0 * (FMIN + (1.0f - FMIN) * expf(-powf(ac / (AC + 1.0f), 1.0f / ALPHA)));

  Cst[ 0*NG+n] = TT;            Cst[ 1*NG+n] = CFMAX * DTC;
  Cst[ 2*NG+n] = CFR*CFMAX*DTC; Cst[ 3*NG+n] = CWH;
  Cst[ 4*NG+n] = fmx;           Cst[ 5*NG+n] = 1.0f / FC;
  Cst[ 6*NG+n] = BETA;          Cst[ 7*NG+n] = FC;
  Cst[ 8*NG+n] = Cpar;          Cst[ 9*NG+n] = 1.0f / (LP * FC);
  Cst[10*NG+n] = BETAET;        Cst[11*NG+n] = PERC * DTC;
  Cst[12*NG+n] = K0 * DTC;      Cst[13*NG+n] = UZL;
  Cst[14*NG+n] = K1 * DTC;      Cst[15*NG+n] = K2 * DTC;

  // routing weights (gamma kernel), normalized
  float a   = fmaxf(p2[n*3+0] * 5.0f,  0.01f);
  float b   = fmaxf(p2[n*3+1] * 12.0f, 0.01f);
  float lag = p2[n*3+2] * 48.0f + RT;
  float am1 = a - 1.0f, invb = 1.0f / b;
  float sum = 0.0f;
  for (int k = 0; k < LENFT; k++) {
    float s  = (k + 0.5f) - lag;
    float sm = fmaxf(s, 1e-6f);
    float wv = (s > 0.0f) ? expf(am1 * logf(sm) - sm * invb) : 0.0f;
    sum += wv;
  }
  float inv = 1.0f / (sum + 1e-8f);
  for (int k = 0; k < LENFT; k++) {
    float s  = (k + 0.5f) - lag;
    float sm = fmaxf(s, 1e-6f);
    float wv = (s > 0.0f) ? expf(am1 * logf(sm) - sm * invb) : 0.0f;
    W[k*NG + n] = wv * inv;
  }
}

// ---------------------------------------------------------------------------
// Kernel 2: sequential HBV scan with ASYNC LDS staging.
// r6/r8 diagnosis: compiler JIT-loads x (VGPR 48/64 -> register prefetch
// impossible) => every step pays ~load latency: 400 cyc/step, 3.7 GB/s/CU in
// both geometries. Fix: global_load_lds ring (16 steps in flight, 32 slots),
// counted s_waitcnt vmcnt(42) (=3*(16-2), never 0) -> loads stay async;
// LDS->reg read one step ahead hides ds latency. 1 wave/block, no barriers.
// ---------------------------------------------------------------------------
struct HbvConst {
  float TT, CFMAXDT, CFRDT, CWH, FMX, IFC, BETA, FC, C, ILF, BETAET,
        PERCDT, K0DT, UZL, K1DT, K2DT;
};

__device__ __forceinline__ void load_const(const float* __restrict__ Cst,
                                           int n, HbvConst& c) {
  c.TT    =Cst[ 0*NG+n]; c.CFMAXDT=Cst[ 1*NG+n]; c.CFRDT =Cst[ 2*NG+n];
  c.CWH   =Cst[ 3*NG+n]; c.FMX    =Cst[ 4*NG+n]; c.IFC   =Cst[ 5*NG+n];
  c.BETA  =Cst[ 6*NG+n]; c.FC     =Cst[ 7*NG+n]; c.C     =Cst[ 8*NG+n];
  c.ILF   =Cst[ 9*NG+n]; c.BETAET =Cst[10*NG+n]; c.PERCDT=Cst[11*NG+n];
  c.K0DT  =Cst[12*NG+n]; c.UZL    =Cst[13*NG+n]; c.K1DT  =Cst[14*NG+n];
  c.K2DT  =Cst[15*NG+n];
}

__device__ __forceinline__ float hbv_step(float P, float Tm, float PET,
    const HbvConst& c, float& SP, float& MW, float& SM, float& SUZ, float& SLZ)
{
  float rain = (Tm >= c.TT) ? P : 0.0f;
  float snow = P - rain;
  SP += snow;
  float dT   = Tm - c.TT;
  float melt = fminf(fmaxf(c.CFMAXDT * dT, 0.0f), SP);
  MW += melt; SP -= melt;
  float refr = fminf(fmaxf(c.CFRDT * (-dT), 0.0f), MW);
  SP += refr; MW -= refr;
  float tosoil = fmaxf(MW - c.CWH * SP, 0.0f);
  MW -= tosoil;
  float win   = rain + tosoil;
  float infil = fminf(win, c.FMX);
  float qie   = win - infil;
  float sw    = fminf(fexp2(c.BETA * flog2(SM * c.IFC)), 1.0f);
  float rech  = infil * sw;
  SM += infil - rech;
  float excess = fmaxf(SM - c.FC, 0.0f);
  SM -= excess;
  float cap = fminf(SLZ, c.C * SLZ * (1.0f - fminf(SM * c.IFC, 1.0f)));
  SM += cap; SLZ -= cap;
  float ef = fminf(fexp2(c.BETAET * flog2(SM * c.ILF)), 1.0f);
  float et = fminf(PET * ef, SM);
  SM = fmaxf(SM - et, NEARZEROC);
  SUZ += rech + excess;
  float perc = fminf(SUZ, c.PERCDT);
  SUZ -= perc;
  float q0 = c.K0DT * fmaxf(SUZ - c.UZL, 0.0f);
  SUZ -= q0;
  float q1 = c.K1DT * SUZ;
  SUZ -= q1;
  SLZ += perc;
  float q2 = c.K2DT * SLZ;
  SLZ -= q2;
  return qie + q0 + q1 + q2;
}

#define SDEPTH 16      // steps in flight
#define SRING  32      // LDS ring slots (2x depth: no WAR hazard)
// counted wait: 3 glls/step * (SDEPTH-2) younger steps may stay outstanding
#define WAITC() asm volatile("s_waitcnt vmcnt(42)" ::: "memory")

typedef const void __attribute__((address_space(1))) gas_void;
typedef void __attribute__((address_space(3)))       las_void;

__global__ __launch_bounds__(64) void scan_kernel(
    const float* __restrict__ x, const float* __restrict__ Cst,
    float* __restrict__ Q)
{
  __shared__ float sx[SRING * 192];   // 24 KB: ring of [step][192 floats]
  const int tid = threadIdx.x;
  const int n   = blockIdx.x * 64 + tid;     // NG = 125*64 exact, no guard

  HbvConst c; load_const(Cst, n, c);
  float SP=1e-3f, MW=1e-3f, SM=1e-3f, SUZ=1e-3f, SLZ=1e-3f;
  float* Qp = Q + n;
  const float* xg = x + (size_t)blockIdx.x * 192;   // block's 192-float row

  // issue the 3 async 256B chunks staging step s into its ring slot
  auto issue3 = [&](int s) {
    const float* g = xg + (size_t)s * (NG * 3);
    float* lb = &sx[(s & (SRING - 1)) * 192];
    __builtin_amdgcn_global_load_lds((gas_void*)(g + tid),       (las_void*)(lb),       4, 0, 0);
    __builtin_amdgcn_global_load_lds((gas_void*)(g + 64 + tid),  (las_void*)(lb + 64),  4, 0, 0);
    __builtin_amdgcn_global_load_lds((gas_void*)(g + 128 + tid), (las_void*)(lb + 128), 4, 0, 0);
  };
  auto lds3 = [&](int s) {
    int b = (s & (SRING - 1)) * 192 + 3 * tid;
    return make_float3(sx[b], sx[b + 1], sx[b + 2]);
  };

  // prologue: fill the pipe with SDEPTH steps, ensure steps 0,1 resident
  for (int d = 0; d < SDEPTH; ++d) issue3(d);
  WAITC();
  float3 rA = lds3(0), rB;

  int t = 0;
  for (; t < TS - SDEPTH; t += 2) {
    rB = lds3(t + 1);                              // resident per prior wait
    Qp[(size_t)t * NG] = hbv_step(rA.x, rA.y, rA.z, c, SP, MW, SM, SUZ, SLZ);
    issue3(t + SDEPTH);
    WAITC();                                       // step t+2 now resident
    rA = lds3(t + 2);
    Qp[(size_t)(t + 1) * NG] = hbv_step(rB.x, rB.y, rB.z, c, SP, MW, SM, SUZ, SLZ);
    issue3(t + SDEPTH + 1);
    WAITC();                                       // step t+3 now resident
  }
  // epilogue: all remaining steps already in LDS
  asm volatile("s_waitcnt vmcnt(0)" ::: "memory");
  for (; t < TS; ++t) {
    float3 nb = (t + 1 < TS) ? lds3(t + 1) : rA;
    Qp[(size_t)t * NG] = hbv_step(rA.x, rA.y, rA.z, c, SP, MW, SM, SUZ, SLZ);
    rA = nb;
  }
}

// ---------------------------------------------------------------------------
// Kernel 3: fused routing FIR (72 taps) + partial einsum.
// einsum G in registers (global float4, L2-hot), Rs read as broadcast float4.
// ---------------------------------------------------------------------------
#define TTILE 32
#define NTILES_T 45          // 1440 / 32
#define NSPLIT 25
#define SUBS 5               // subtiles per split (25*5*64 = 8000)
#define QROWS (TTILE + 71)   // 103

__global__ __launch_bounds__(256, 2) void route_kernel(
    const float* __restrict__ Q, const float* __restrict__ W,
    const float* __restrict__ topo, const float* __restrict__ areas,
    float* __restrict__ Par)   // [NSPLIT][TS][NOUT]
{
  __shared__ float Qs[QROWS][64];   // 26.4 KB
  __shared__ float Ws[LENFT][64];   // 18.4 KB
  __shared__ float Rs[TTILE][68];   //  8.7 KB (pad 68: float4-aligned rows)

  int tile  = blockIdx.x;           // 0..44
  int split = blockIdx.y;           // 0..24
  int t0    = tile * TTILE;
  int tid   = threadIdx.x;

  int nn = tid & 63;                // conv: cell within subtile
  int tc = (tid >> 6) * 8;          // conv: 8 consecutive t-rows
  int oe = tid & 31;                // einsum: outlet
  int te = (tid >> 5) * 4;          // einsum: 4 consecutive t-rows

  float acc_out[4] = {0.f, 0.f, 0.f, 0.f};

  for (int sub = 0; sub < SUBS; sub++) {
    int n0 = (split * SUBS + sub) * 64;

    // G for this subtile into registers (coalesced row reads, L2-hot)
    float4 Greg[16];
    #pragma unroll
    for (int g4 = 0; g4 < 16; g4++) {
      float4 tv = *reinterpret_cast<const float4*>(&topo[oe * NG + n0 + g4 * 4]);
      float4 av = *reinterpret_cast<const float4*>(&areas[n0 + g4 * 4]);
      Greg[g4] = make_float4(tv.x * av.x, tv.y * av.y, tv.z * av.z, tv.w * av.w);
    }

    if (sub) __syncthreads();       // prev einsum reads done before reload
    for (int idx = tid; idx < QROWS * 64; idx += 256) {
      int rr = idx >> 6, cc = idx & 63;
      int t  = t0 - 71 + rr;
      Qs[rr][cc] = (t >= 0) ? Q[t * NG + n0 + cc] : 0.0f;
    }
    for (int idx = tid; idx < LENFT * 64; idx += 256) {
      int k = idx >> 6, cc = idx & 63;
      Ws[k][cc] = W[k * NG + n0 + cc];
    }
    __syncthreads();

    // ---- conv: 8 outputs/thread, sliding 8-register window over Q rows ----
    float acc[8];
    float qwin[8];
    #pragma unroll
    for (int i = 0; i < 8; i++) { acc[i] = 0.0f; qwin[i] = Qs[tc + i][nn]; }
    #pragma unroll
    for (int kk = 0; kk < LENFT; kk++) {
      float w = Ws[71 - kk][nn];
      #pragma unroll
      for (int i = 0; i < 8; i++) acc[i] += w * qwin[i];
      #pragma unroll
      for (int i = 0; i < 7; i++) qwin[i] = qwin[i + 1];
      if (kk < 71) qwin[7] = Qs[tc + 8 + kk][nn];
    }
    #pragma unroll
    for (int i = 0; i < 8; i++) Rs[tc + i][nn] = acc[i];
    __syncthreads();

    // ---- einsum: 4 (t,o) outputs/thread; Rs as broadcast float4 ----
    #pragma unroll
    for (int g4 = 0; g4 < 16; g4++) {
      float4 g = Greg[g4];
      #pragma unroll
      for (int p = 0; p < 4; p++) {
        float4 r = *reinterpret_cast<const float4*>(&Rs[te + p][g4 * 4]);
        acc_out[p] += r.x * g.x + r.y * g.y + r.z * g.z + r.w * g.w;
      }
    }
  }

  #pragma unroll
  for (int p = 0; p < 4; p++) {
    int tg = t0 + te + p;           // always < 1440 (45*32 exact)
    Par[(split * TS + tg) * NOUT + oe] = acc_out[p];
  }
}

// ---------------------------------------------------------------------------
// Kernel 4: reduce partials over the 25 n-splits
// ---------------------------------------------------------------------------
__global__ __launch_bounds__(256) void reduce_kernel(
    const float* __restrict__ Par, float* __restrict__ out)
{
  int i = blockIdx.x * 256 + threadIdx.x;
  if (i < TS * NOUT) {
    float s = 0.0f;
    #pragma unroll
    for (int sp = 0; sp < NSPLIT; sp++) s += Par[sp * (TS * NOUT) + i];
    out[i] = s;
  }
}

// ---------------------------------------------------------------------------
extern "C" void kernel_launch(void* const* d_in, const int* in_sizes, int n_in,
                              void* d_out, int out_size, void* d_ws, size_t ws_size,
                              hipStream_t stream)
{
  const float* x_phy  = (const float*)d_in[0];
  const float* ac_all = (const float*)d_in[1];
  // d_in[2] = elev_all (unused by reference)
  const float* topo   = (const float*)d_in[3];
  const float* areas  = (const float*)d_in[4];
  const float* p1     = (const float*)d_in[5];
  const float* p2     = (const float*)d_in[6];
  float* out = (float*)d_out;

  char* ws = (char*)d_ws;
  float* Q   = (float*)(ws);                                  // 46,080,000 B
  float* W   = (float*)(ws + 46080000);                       //  2,304,000 B
  float* Cst = (float*)(ws + 46080000 + 2304000);             //    512,000 B
  float* Par = (float*)(ws + 46080000 + 2304000 + 512000);    //  4,608,000 B

  hipLaunchKernelGGL(precompute_kernel, dim3(32), dim3(256), 0, stream,
                     p1, p2, ac_all, Cst, W);
  hipLaunchKernelGGL(scan_kernel, dim3(NG / 64), dim3(64), 0, stream,
                     x_phy, Cst, Q);
  hipLaunchKernelGGL(route_kernel, dim3(NTILES_T, NSPLIT), dim3(256), 0, stream,
                     Q, W, topo, areas, Par);
  hipLaunchKernelGGL(reduce_kernel, dim3((TS * NOUT + 255) / 256), dim3(256), 0, stream,
                     Par, out);
}